// Round 5
// baseline (1001.041 us; speedup 1.0000x reference)
//
#include <hip/hip_runtime.h>
#include <cstddef>

#define B_    4
#define T_    16384
#define FOUT_ 14337
#define FOUTP 14464                       // 113*128, frag-tile padded
#define NL_   20
#define XSTR  ((size_t)T_*128)            // x per-b stride (halfs)
#define ABSTR ((size_t)FOUTP*128)         // acts per-b stride (halfs)
#define ALSTR ((size_t)B_*FOUTP*128)      // acts per-l stride
#define SBSTR ((size_t)FOUTP*512)         // skip/h1 per-b stride

typedef float    f32x16 __attribute__((ext_vector_type(16)));
typedef _Float16 f16x8  __attribute__((ext_vector_type(8)));

// ---- static device buffers (zero-init at load; pad regions never written) ----
__device__ _Float16 g_xh0[(size_t)B_*T_*128];
__device__ _Float16 g_xh1[(size_t)B_*T_*128];
__device__ _Float16 g_WdF0[(size_t)NL_*256*128];   // frag layout, K=128, tap0
__device__ _Float16 g_WdF1[(size_t)NL_*256*128];   // tap1
__device__ _Float16 g_WrF [(size_t)NL_*128*128];
__device__ _Float16 g_WsF [(size_t)512*2560];
__device__ _Float16 g_W1F [(size_t)512*512];
__device__ _Float16 g_W2F [(size_t)256*512];
__device__ float    g_bssum[512];
__device__ _Float16 g_acts[(size_t)NL_*B_*FOUTP*128];  // B-frag layout per (l,b), rows ts, K=128
__device__ _Float16 g_skipF[(size_t)B_*FOUTP*512];     // B-frag layout, rows ts, K=512
__device__ _Float16 g_h1F [(size_t)B_*FOUTP*512];

__device__ __forceinline__ float sigm_(float x){ return 1.0f/(1.0f+__expf(-x)); }
__device__ __forceinline__ float tanh_(float x){ return 1.0f - 2.0f/(__expf(2.0f*x)+1.0f); }
__device__ __forceinline__ f32x16 MFMA32(f16x8 a, f16x8 b, f32x16 c){
  return __builtin_amdgcn_mfma_f32_32x32x16_f16(a, b, c, 0, 0, 0);
}
// Fragment layout (A rows=m / B rows=n): per 32-row tile, per k-step(16):
// 1KB block, element(row,k): lane = ((k>>3)&1)*32 + (row&31), j = k&7.

// async global->LDS: per-lane 16B from g, lands at (wave-uniform) l + lane*16
typedef const __attribute__((address_space(1))) _Float16 gash;
typedef __attribute__((address_space(3))) _Float16 lash;
__device__ __forceinline__ void gld_lds16(const _Float16* g, _Float16* l){
  __builtin_amdgcn_global_load_lds((gash*)g, (lash*)l, 16, 0, 0);
}

// ---------------- weight conversion ----------------
__global__ void cvt_wd(const float* __restrict__ Wd){
  int i = blockIdx.x*256 + threadIdx.x;
  if (i >= NL_*256*16) return;
  int row = i >> 4, koct = i & 15;
  const float* s = Wd + ((size_t)row*128 + koct*8)*2;
  int lane = (koct&1)*32 + (row&31);
  size_t addr = (size_t)((row>>5)*8 + (koct>>1))*512 + lane*8;
  union { _Float16 h[8]; uint4 v; } u0, u1;
#pragma unroll
  for (int j=0;j<8;j++){ u0.h[j]=(_Float16)s[2*j]; u1.h[j]=(_Float16)s[2*j+1]; }
  *(uint4*)((void*)(g_WdF0 + addr)) = u0.v;
  *(uint4*)((void*)(g_WdF1 + addr)) = u1.v;
}
__global__ void cvt_rm(const float* __restrict__ src, int which, int M, int K){
  int i = blockIdx.x*256 + threadIdx.x;
  if (i >= M*(K>>3)) return;
  int row = i / (K>>3), koct = i % (K>>3);
  const float* s = src + (size_t)row*K + koct*8;
  int lane = (koct&1)*32 + (row&31);
  size_t addr = ((size_t)(row>>5)*(K>>4) + (koct>>1))*512 + lane*8;
  union { _Float16 h[8]; uint4 v; } u;
#pragma unroll
  for (int j=0;j<8;j++) u.h[j]=(_Float16)s[j];
  _Float16* dst = (which==0)?g_WrF:(which==1)?g_W1F:g_W2F;
  *(uint4*)((void*)(dst + addr)) = u.v;
}
__global__ void cvt_ws(const float* __restrict__ Ws){
  int i = blockIdx.x*256 + threadIdx.x;
  if (i >= NL_*512*16) return;
  int l = i >> 13, o = (i>>4)&511, coct = i&15;
  const float* s = Ws + ((size_t)(l*512+o))*128 + coct*8;
  int lane = (coct&1)*32 + (o&31);
  size_t addr = ((size_t)(o>>5)*160 + (size_t)(l*8 + (coct>>1)))*512 + lane*8;
  union { _Float16 h[8]; uint4 v; } u;
#pragma unroll
  for (int j=0;j<8;j++) u.h[j]=(_Float16)s[j];
  *(uint4*)((void*)(g_WsF + addr)) = u.v;
}
__global__ void bssum_k(const float* __restrict__ bs){
  int o = threadIdx.x;
  float s = 0.f;
  for (int l=0;l<NL_;l++) s += bs[l*512 + o];
  g_bssum[o] = s;
}

// ---------------- embedding -> fp16 x0 ----------------
__global__ void embed_kernel(const int* __restrict__ y, const float* __restrict__ embed){
  int gid = blockIdx.x*256 + threadIdx.x;
  int bt = gid >> 4, c8 = gid & 15;
  if (bt < B_*T_){
    int idx = y[bt];
    const float* e = embed + (size_t)idx*128 + c8*8;
    union { _Float16 h[8]; uint4 v; } u;
#pragma unroll
    for (int j=0;j<8;j++) u.h[j]=(_Float16)e[j];
    *(uint4*)((void*)(g_xh0 + (size_t)bt*128 + c8*8)) = u.v;
  }
}

// ---------------- fused layer v2: 128-t tiles, 8 waves, XOR-swizzled LDS ----
// 512 threads = 8 waves; wave w = (wm = w&3, wn = w>>2).
// Phase B: wave computes m-tiles {wm (tanh), 4+wm (sigm)} x n-tiles {2wn, 2wn+1}.
// Phase C: wave computes m-tile wm x n-tiles {2wn, 2wn+1}.
// LDS: X0s/X1s [16 rows][128 t] halfs, 16B-chunk XOR swizzle:
//   half_off(r,t) = r*1024 + 8*(t ^ (r&7))   (+ sub-offset<8 inside chunk)
// -> stage writes (c16 varies, t fixed) and frag reads (t varies) both
//    conflict-free; total LDS = 2 x 32 KB = 64 KB; ACs aliases X0s.
__device__ __forceinline__ int xh_(int r, int t){ return r*1024 + ((t ^ (r&7))*8); }

__global__ __launch_bounds__(512,4) void layer16(
    int swap, int l, int d, int Tout, int ss,
    const float* __restrict__ bd_l, const float* __restrict__ br_l)
{
  const _Float16* __restrict__ xin  = swap ? g_xh1 : g_xh0;
  _Float16* __restrict__       xout = swap ? g_xh0 : g_xh1;

  __shared__ _Float16 X0s[16*1024];
  __shared__ _Float16 X1s[16*1024];
  _Float16* ACs = X0s;                 // aliased after phase B

  const int tid = threadIdx.x;
  const int w   = tid >> 6;
  const int lane= tid & 63;
  const int ln2 = lane & 31;
  const int h   = lane >> 5;
  const int wm  = w & 3;
  const int wn  = w >> 2;
  const int b   = blockIdx.y;
  const int t0  = blockIdx.x*128;
  const int ntv = min(128, Tout - t0);
  const int limit = Tout + d - 1;
  const _Float16* __restrict__ xb = xin + (size_t)b*XSTR;

  // ---- stage both taps: per thread 4 (t,c16) pairs
#pragma unroll
  for (int it=0; it<4; it++){
    int t = (tid>>4) + it*32, c16 = tid&15;
    int s0 = t0 + t;     if (s0 > limit) s0 = limit;
    int s1 = t0 + t + d; if (s1 > limit) s1 = limit;
    *(uint4*)((void*)&X0s[xh_(c16,t)]) = *(const uint4*)((const void*)(xb + (size_t)s0*128 + c16*8));
    *(uint4*)((void*)&X1s[xh_(c16,t)]) = *(const uint4*)((const void*)(xb + (size_t)s1*128 + c16*8));
  }
  __syncthreads();

  // ---- Phase B: in_act[256][128]
  f32x16 aB[2][2];
#pragma unroll
  for (int mi=0;mi<2;mi++)
#pragma unroll
    for (int nt=0;nt<2;nt++)
#pragma unroll
      for (int r=0;r<16;r++) aB[mi][nt][r] = 0.f;

#pragma unroll
  for (int tap=0; tap<2; tap++){
    const _Float16* __restrict__ Xs = tap ? X1s : X0s;
    const _Float16* __restrict__ Wt = (tap ? g_WdF1 : g_WdF0) + (size_t)l*32768;
    const _Float16* aT = Wt + (size_t)wm*4096 + lane*8;
    const _Float16* aS = Wt + (size_t)(4+wm)*4096 + lane*8;
#pragma unroll
    for (int ks=0; ks<8; ks++){
      f16x8 bfr[2];
#pragma unroll
      for (int nt=0; nt<2; nt++)
        bfr[nt] = *(const f16x8*)((const void*)&Xs[xh_(ks*2+h, (wn*2+nt)*32+ln2)]);
      f16x8 fT = *(const f16x8*)((const void*)(aT + ks*512));
      f16x8 fS = *(const f16x8*)((const void*)(aS + ks*512));
#pragma unroll
      for (int nt=0; nt<2; nt++){
        aB[0][nt] = MFMA32(fT, bfr[nt], aB[0][nt]);
        aB[1][nt] = MFMA32(fS, bfr[nt], aB[1][nt]);
      }
    }
  }
  __syncthreads();   // all phase-B reads of X0s done before ACs (alias) writes

  // ---- gate -> ACs
#pragma unroll
  for (int nt=0; nt<2; nt++)
#pragma unroll
    for (int rq=0; rq<4; rq++){
      int c0 = wm*32 + rq*8 + 4*h;
      union { _Float16 hh[4]; ushort4 v; } pk;
#pragma unroll
      for (int rr=0; rr<4; rr++){
        float it_ = aB[0][nt][rq*4+rr] + bd_l[c0+rr];
        float is_ = aB[1][nt][rq*4+rr] + bd_l[128+c0+rr];
        pk.hh[rr] = (_Float16)(tanh_(it_)*sigm_(is_));
      }
      *(ushort4*)((void*)&ACs[xh_(wm*4+rq, (wn*2+nt)*32+ln2) + 4*h]) = pk.v;
    }
  __syncthreads();

  // ---- Phase C: res[128][128] = Wr@acts
  f32x16 aC[2];
#pragma unroll
  for (int nt=0;nt<2;nt++)
#pragma unroll
    for (int r=0;r<16;r++) aC[nt][r] = 0.f;
  {
    const _Float16* aW = g_WrF + (size_t)l*16384 + (size_t)wm*4096 + lane*8;
#pragma unroll
    for (int ks=0; ks<8; ks++){
      f16x8 bfr[2];
#pragma unroll
      for (int nt=0; nt<2; nt++)
        bfr[nt] = *(const f16x8*)((const void*)&ACs[xh_(ks*2+h, (wn*2+nt)*32+ln2)]);
      f16x8 fW = *(const f16x8*)((const void*)(aW + ks*512));
#pragma unroll
      for (int nt=0; nt<2; nt++)
        aC[nt] = MFMA32(fW, bfr[nt], aC[nt]);
    }
  }

  // ---- epilogue: x_new = res + br + x[t+d] (from X1s), store fp16
#pragma unroll
  for (int nt=0; nt<2; nt++){
    int t = (wn*2+nt)*32 + ln2;
    if (t < ntv){
      size_t xrow = (size_t)b*XSTR + (size_t)(t0+t)*128;
#pragma unroll
      for (int rq=0; rq<4; rq++){
        int c0 = wm*32 + rq*8 + 4*h;
        union { ushort4 v; _Float16 hh[4]; } xr;
        xr.v = *(const ushort4*)((const void*)&X1s[xh_(wm*4+rq, t) + 4*h]);
        union { _Float16 hh[4]; ushort4 v; } ov;
#pragma unroll
        for (int rr=0; rr<4; rr++)
          ov.hh[rr] = (_Float16)(aC[nt][rq*4+rr] + br_l[c0+rr] + (float)xr.hh[rr]);
        *(ushort4*)((void*)(xout + xrow + c0)) = ov.v;
      }
    }
  }

  // ---- acts -> global B-frag layout indexed by ts
  _Float16* __restrict__ actsB = g_acts + (size_t)l*ALSTR + (size_t)b*ABSTR;
#pragma unroll
  for (int it=0; it<4; it++){
    int t = (tid>>4) + it*32, c16 = tid&15;
    int ts = t0 + t - ss;
    if (t < ntv && ts >= 0 && ts < FOUT_){
      size_t addr = (size_t)(ts>>5)*4096 + (size_t)(c16>>1)*512 + ((c16&1)*32 + (ts&31))*8;
      *(uint4*)((void*)(actsB + addr)) = *(const uint4*)((const void*)&ACs[xh_(c16,t)]);
    }
  }
}

// ---------------- streaming GEMMs: 4-buffer LDS pipeline, 2 blocks/CU ----------------
// (unchanged from round 4)
template<int MODE>
__global__ __launch_bounds__(512,4) void gemm_stream(float* __restrict__ outF){
  constexpr int NSTEP = (MODE==0)?160:32;     // k-steps of 16
  constexpr int NSC   = NSTEP/4;              // sub-chunks of 4 ks: 40 or 8
  const _Float16* __restrict__ A    = (MODE==0)?g_WsF:(MODE==1)?g_W1F:g_W2F;
  const _Float16* __restrict__ Bsrc = (MODE==0)?g_acts:(MODE==1)?g_skipF:g_h1F;

  __shared__ __align__(16) _Float16 Bs[4][8192];   // 4 x 16KB

  const int tid = threadIdx.x;
  const int w   = tid >> 6;
  const int lane= tid & 63;
  const int ln2 = lane & 31;
  const int h   = lane >> 5;
  const int b   = blockIdx.z;
  const int ts0 = blockIdx.y*128;
  const int mtile = blockIdx.x*8 + w;       // this wave's m-tile (32 rows)

  const _Float16* Gq[2];
#pragma unroll
  for (int q=0;q<2;q++){
    int nt = (w*2+q)&3;
    size_t tile = (size_t)blockIdx.y*4 + nt;
    Gq[q] = (MODE==0) ? (Bsrc + (size_t)b*ABSTR + tile*4096  + lane*8)
                      : (Bsrc + (size_t)b*SBSTR + tile*16384 + lane*8);
  }

  const _Float16* Aw = A + (size_t)mtile*((size_t)NSTEP*512) + lane*8;

  f32x16 acc[4];
#pragma unroll
  for (int nt=0;nt<4;nt++)
#pragma unroll
    for (int r=0;r<16;r++) acc[nt][r] = 0.f;

  auto STAGE = [&](int buf, int sc){
#pragma unroll
    for (int q=0;q<2;q++){
      int bi   = w*2 + q;
      int kslq = bi>>2;
      const _Float16* g;
      if (MODE==0){
        int ks = sc*4 + kslq;
        g = Gq[q] + (size_t)(ks>>3)*ALSTR + (size_t)(ks&7)*512;
      } else {
        g = Gq[q] + (size_t)(sc*4 + kslq)*512;
      }
      gld_lds16(g, &Bs[buf][(size_t)bi*512]);
    }
  };

  STAGE(0,0);
  STAGE(1,1);
  asm volatile("s_waitcnt vmcnt(2)" ::: "memory");
  __builtin_amdgcn_sched_barrier(0);
  __builtin_amdgcn_s_barrier();

  for (int c=0; c<NSC; ++c){
    const int buf = c & 3;
    f16x8 af[4];
#pragma unroll
    for (int j=0;j<4;j++)
      af[j] = *(const f16x8*)((const void*)(Aw + (size_t)(c*4+j)*512));
    __builtin_amdgcn_sched_barrier(0);
    if (c+2 < NSC) STAGE((c+2)&3, c+2);
    __builtin_amdgcn_sched_barrier(0);
#pragma unroll
    for (int j=0;j<4;j++){
      f16x8 bfr[4];
#pragma unroll
      for (int nt=0;nt<4;nt++)
        bfr[nt] = *(const f16x8*)((const void*)&Bs[buf][(size_t)(j*4+nt)*512 + lane*8]);
#pragma unroll
      for (int nt=0;nt<4;nt++)
        acc[nt] = MFMA32(af[j], bfr[nt], acc[nt]);
    }
    __builtin_amdgcn_sched_barrier(0);
    __builtin_amdgcn_s_barrier();
  }

  if (MODE != 2){
    _Float16* __restrict__ dstb = ((MODE==0)?g_skipF:g_h1F) + (size_t)b*SBSTR;
#pragma unroll
    for (int nt=0; nt<4; nt++){
      int ts = ts0 + nt*32 + ln2;
      if (ts >= FOUT_) continue;
#pragma unroll
      for (int rq=0; rq<4; rq++){
        int m0 = mtile*32 + rq*8 + 4*h;
        union { _Float16 hh[4]; ushort4 v; } pk;
#pragma unroll
        for (int rr=0; rr<4; rr++){
          float vv = acc[nt][rq*4+rr];
          if (MODE==0) vv += g_bssum[m0+rr];
          pk.hh[rr] = (_Float16)fmaxf(vv, 0.f);
        }
        size_t addr = (size_t)(ts>>5)*16384 + (size_t)(mtile*2 + (rq>>1))*512
                    + ((rq&1)*32 + (ts&31))*8 + 4*h;
        *(ushort4*)((void*)(dstb + addr)) = pk.v;
      }
    }
  } else {
#pragma unroll
    for (int nt=0; nt<4; nt++){
      int ts = ts0 + nt*32 + ln2;
      if (ts >= FOUT_) continue;
#pragma unroll
      for (int rq=0; rq<4; rq++){
        int m0 = w*32 + rq*8 + 4*h;
#pragma unroll
        for (int rr=0; rr<4; rr++)
          outF[((size_t)(b*256 + m0 + rr))*FOUT_ + ts] = acc[nt][rq*4+rr];
      }
    }
  }
}

// ---------------- host launch ----------------
extern "C" void kernel_launch(void* const* d_in, const int* in_sizes, int n_in,
                              void* d_out, int out_size, void* d_ws, size_t ws_size,
                              hipStream_t stream) {
  const int*   y     = (const int*)  d_in[0];
  const float* embed = (const float*)d_in[1];
  const float* Wd    = (const float*)d_in[2];
  const float* bd    = (const float*)d_in[3];
  const float* Ws    = (const float*)d_in[4];
  const float* bs    = (const float*)d_in[5];
  const float* Wr    = (const float*)d_in[6];
  const float* br    = (const float*)d_in[7];
  const float* W1    = (const float*)d_in[8];
  const float* W2    = (const float*)d_in[9];
  float* out = (float*)d_out;
  (void)d_ws; (void)ws_size;

  cvt_wd<<<dim3(320), dim3(256), 0, stream>>>(Wd);
  cvt_rm<<<dim3(160), dim3(256), 0, stream>>>(Wr, 0, NL_*128, 128);
  cvt_rm<<<dim3(128), dim3(256), 0, stream>>>(W1, 1, 512, 512);
  cvt_rm<<<dim3( 64), dim3(256), 0, stream>>>(W2, 2, 256, 512);
  cvt_ws<<<dim3(640), dim3(256), 0, stream>>>(Ws);
  bssum_k<<<dim3(1), dim3(512), 0, stream>>>(bs);

  embed_kernel<<<dim3((B_*T_*16)/256), dim3(256), 0, stream>>>(y, embed);

  static const int DIL[NL_] = {1,2,4,8,16,32,64,128,256,512,
                               1,2,4,8,16,32,64,128,256,512};
  int swap = 0;
  int Tin = T_;
  for (int i=0;i<NL_;i++){
    int d = DIL[i];
    int Tout = Tin - d;
    dim3 grid((Tout+127)/128, B_);
    layer16<<<grid, dim3(512), 0, stream>>>(
        swap, i, d, Tout, Tout - FOUT_, bd + (size_t)i*256, br + (size_t)i*128);
    swap ^= 1;
    Tin = Tout;
  }

  // m-split fastest (blockIdx.x) so m-siblings dispatch adjacently (B dedupe)
  gemm_stream<0><<<dim3(2, FOUTP/128, B_), dim3(512), 0, stream>>>(nullptr);
  gemm_stream<1><<<dim3(2, FOUTP/128, B_), dim3(512), 0, stream>>>(nullptr);
  gemm_stream<2><<<dim3(1, FOUTP/128, B_), dim3(512), 0, stream>>>(out);
}

// Round 6
// 924.125 us; speedup vs baseline: 1.0832x; 1.0832x over previous
//
#include <hip/hip_runtime.h>
#include <cstddef>

#define B_    4
#define T_    16384
#define FOUT_ 14337
#define FOUTP 14464                       // 113*128, frag-tile padded
#define NL_   20
#define XSTR  ((size_t)T_*128)            // x per-b stride (halfs)
#define ABSTR ((size_t)FOUTP*128)         // acts per-b stride (halfs)
#define ALSTR ((size_t)B_*FOUTP*128)      // acts per-l stride
#define SBSTR ((size_t)FOUTP*512)         // skip/h1 per-b stride

typedef float    f32x16 __attribute__((ext_vector_type(16)));
typedef _Float16 f16x8  __attribute__((ext_vector_type(8)));

// ---- static device buffers (zero-init at load; pad regions never written) ----
__device__ _Float16 g_xh0[(size_t)B_*T_*128];
__device__ _Float16 g_xh1[(size_t)B_*T_*128];
__device__ _Float16 g_WdF0[(size_t)NL_*256*128];   // frag layout, K=128, tap0
__device__ _Float16 g_WdF1[(size_t)NL_*256*128];   // tap1
__device__ _Float16 g_WrF [(size_t)NL_*128*128];
__device__ _Float16 g_WsF [(size_t)512*2560];
__device__ _Float16 g_W1F [(size_t)512*512];
__device__ _Float16 g_W2F [(size_t)256*512];
__device__ float    g_bssum[512];
__device__ _Float16 g_acts[(size_t)NL_*B_*FOUTP*128];  // B-frag layout per (l,b), rows ts, K=128
__device__ _Float16 g_skipF[(size_t)B_*FOUTP*512];     // B-frag layout, rows ts, K=512
__device__ _Float16 g_h1F [(size_t)B_*FOUTP*512];

__device__ __forceinline__ float sigm_(float x){ return 1.0f/(1.0f+__expf(-x)); }
__device__ __forceinline__ float tanh_(float x){ return 1.0f - 2.0f/(__expf(2.0f*x)+1.0f); }
__device__ __forceinline__ f32x16 MFMA32(f16x8 a, f16x8 b, f32x16 c){
  return __builtin_amdgcn_mfma_f32_32x32x16_f16(a, b, c, 0, 0, 0);
}
// Fragment layout (A rows=m / B rows=n): per 32-row tile, per k-step(16):
// 1KB block, element(row,k): lane = ((k>>3)&1)*32 + (row&31), j = k&7.

// async global->LDS: per-lane 16B from g, lands at (wave-uniform) l + lane*16
typedef const __attribute__((address_space(1))) _Float16 gash;
typedef __attribute__((address_space(3))) _Float16 lash;
__device__ __forceinline__ void gld_lds16(const _Float16* g, _Float16* l){
  __builtin_amdgcn_global_load_lds((gash*)g, (lash*)l, 16, 0, 0);
}

// ---------------- weight conversion ----------------
__global__ void cvt_wd(const float* __restrict__ Wd){
  int i = blockIdx.x*256 + threadIdx.x;
  if (i >= NL_*256*16) return;
  int row = i >> 4, koct = i & 15;
  const float* s = Wd + ((size_t)row*128 + koct*8)*2;
  int lane = (koct&1)*32 + (row&31);
  size_t addr = (size_t)((row>>5)*8 + (koct>>1))*512 + lane*8;
  union { _Float16 h[8]; uint4 v; } u0, u1;
#pragma unroll
  for (int j=0;j<8;j++){ u0.h[j]=(_Float16)s[2*j]; u1.h[j]=(_Float16)s[2*j+1]; }
  *(uint4*)((void*)(g_WdF0 + addr)) = u0.v;
  *(uint4*)((void*)(g_WdF1 + addr)) = u1.v;
}
__global__ void cvt_rm(const float* __restrict__ src, int which, int M, int K){
  int i = blockIdx.x*256 + threadIdx.x;
  if (i >= M*(K>>3)) return;
  int row = i / (K>>3), koct = i % (K>>3);
  const float* s = src + (size_t)row*K + koct*8;
  int lane = (koct&1)*32 + (row&31);
  size_t addr = ((size_t)(row>>5)*(K>>4) + (koct>>1))*512 + lane*8;
  union { _Float16 h[8]; uint4 v; } u;
#pragma unroll
  for (int j=0;j<8;j++) u.h[j]=(_Float16)s[j];
  _Float16* dst = (which==0)?g_WrF:(which==1)?g_W1F:g_W2F;
  *(uint4*)((void*)(dst + addr)) = u.v;
}
__global__ void cvt_ws(const float* __restrict__ Ws){
  int i = blockIdx.x*256 + threadIdx.x;
  if (i >= NL_*512*16) return;
  int l = i >> 13, o = (i>>4)&511, coct = i&15;
  const float* s = Ws + ((size_t)(l*512+o))*128 + coct*8;
  int lane = (coct&1)*32 + (o&31);
  size_t addr = ((size_t)(o>>5)*160 + (size_t)(l*8 + (coct>>1)))*512 + lane*8;
  union { _Float16 h[8]; uint4 v; } u;
#pragma unroll
  for (int j=0;j<8;j++) u.h[j]=(_Float16)s[j];
  *(uint4*)((void*)(g_WsF + addr)) = u.v;
}
__global__ void bssum_k(const float* __restrict__ bs){
  int o = threadIdx.x;
  float s = 0.f;
  for (int l=0;l<NL_;l++) s += bs[l*512 + o];
  g_bssum[o] = s;
}

// ---------------- embedding -> fp16 x0 ----------------
__global__ void embed_kernel(const int* __restrict__ y, const float* __restrict__ embed){
  int gid = blockIdx.x*256 + threadIdx.x;
  int bt = gid >> 4, c8 = gid & 15;
  if (bt < B_*T_){
    int idx = y[bt];
    const float* e = embed + (size_t)idx*128 + c8*8;
    union { _Float16 h[8]; uint4 v; } u;
#pragma unroll
    for (int j=0;j<8;j++) u.h[j]=(_Float16)e[j];
    *(uint4*)((void*)(g_xh0 + (size_t)bt*128 + c8*8)) = u.v;
  }
}

// ---------------- fused layer: fp16, 32x32x16 MFMA, frag acts output ----------------
// (round-4 v1: 256 threads = 4 waves; block tile 64 t x full channels)
// LDS tile: octet c16 = c>>3, addr = c16*520 + t*8 + (c&7).
__global__ __launch_bounds__(256,3) void layer16(
    int swap, int l, int d, int Tout, int ss,
    const float* __restrict__ bd_l, const float* __restrict__ br_l)
{
  const _Float16* __restrict__ xin  = swap ? g_xh1 : g_xh0;
  _Float16* __restrict__       xout = swap ? g_xh0 : g_xh1;

  __shared__ _Float16 X0s[16*520];
  __shared__ _Float16 X1s[16*520];
  __shared__ _Float16 ACs[16*520];

  const int tid = threadIdx.x;
  const int w   = tid >> 6;
  const int lane= tid & 63;
  const int ln2 = lane & 31;
  const int h   = lane >> 5;
  const int b   = blockIdx.y;
  const int t0  = blockIdx.x*64;
  const int ntv = min(64, Tout - t0);
  const int limit = Tout + d - 1;
  const _Float16* __restrict__ xb = xin + (size_t)b*XSTR;

  // ---- stage both taps
#pragma unroll
  for (int it=0; it<4; it++){
    int t = (tid>>4) + it*16, c16 = tid&15;
    int s0 = t0 + t;     if (s0 > limit) s0 = limit;
    int s1 = t0 + t + d; if (s1 > limit) s1 = limit;
    *(uint4*)((void*)&X0s[c16*520 + t*8]) = *(const uint4*)((const void*)(xb + (size_t)s0*128 + c16*8));
    *(uint4*)((void*)&X1s[c16*520 + t*8]) = *(const uint4*)((const void*)(xb + (size_t)s1*128 + c16*8));
  }
  __syncthreads();

  // ---- Phase B: in_act[256][64]; wave w: m-tiles {w (tanh), 4+w (sigm)}
  f32x16 aB[2][2];
#pragma unroll
  for (int mi=0;mi<2;mi++)
#pragma unroll
    for (int nt=0;nt<2;nt++)
#pragma unroll
      for (int r=0;r<16;r++) aB[mi][nt][r] = 0.f;

#pragma unroll
  for (int tap=0; tap<2; tap++){
    const _Float16* __restrict__ Xs = tap ? X1s : X0s;
    const _Float16* __restrict__ Wt = (tap ? g_WdF1 : g_WdF0) + (size_t)l*32768;
    const _Float16* aT = Wt + (size_t)w*4096 + lane*8;
    const _Float16* aS = Wt + (size_t)(4+w)*4096 + lane*8;
#pragma unroll
    for (int ks=0; ks<8; ks++){
      f16x8 bfr[2];
#pragma unroll
      for (int nt=0; nt<2; nt++)
        bfr[nt] = *(const f16x8*)((const void*)&Xs[(ks*2+h)*520 + (nt*32+ln2)*8]);
      f16x8 fT = *(const f16x8*)((const void*)(aT + ks*512));
      f16x8 fS = *(const f16x8*)((const void*)(aS + ks*512));
#pragma unroll
      for (int nt=0; nt<2; nt++){
        aB[0][nt] = MFMA32(fT, bfr[nt], aB[0][nt]);
        aB[1][nt] = MFMA32(fS, bfr[nt], aB[1][nt]);
      }
    }
  }

  // ---- gate -> ACs
#pragma unroll
  for (int nt=0; nt<2; nt++)
#pragma unroll
    for (int rq=0; rq<4; rq++){
      int c0 = w*32 + rq*8 + 4*h;
      union { _Float16 hh[4]; ushort4 v; } pk;
#pragma unroll
      for (int rr=0; rr<4; rr++){
        float it_ = aB[0][nt][rq*4+rr] + bd_l[c0+rr];
        float is_ = aB[1][nt][rq*4+rr] + bd_l[128+c0+rr];
        pk.hh[rr] = (_Float16)(tanh_(it_)*sigm_(is_));
      }
      *(ushort4*)((void*)&ACs[(w*4+rq)*520 + (nt*32+ln2)*8 + 4*h]) = pk.v;
    }
  __syncthreads();

  // ---- Phase C: res[128][64] = Wr@acts
  f32x16 aC[2];
#pragma unroll
  for (int nt=0;nt<2;nt++)
#pragma unroll
    for (int r=0;r<16;r++) aC[nt][r] = 0.f;
  {
    const _Float16* aW = g_WrF + (size_t)l*16384 + (size_t)w*4096 + lane*8;
#pragma unroll
    for (int ks=0; ks<8; ks++){
      f16x8 bfr[2];
#pragma unroll
      for (int nt=0; nt<2; nt++)
        bfr[nt] = *(const f16x8*)((const void*)&ACs[(ks*2+h)*520 + (nt*32+ln2)*8]);
      f16x8 fW = *(const f16x8*)((const void*)(aW + ks*512));
#pragma unroll
      for (int nt=0; nt<2; nt++)
        aC[nt] = MFMA32(fW, bfr[nt], aC[nt]);
    }
  }

  // ---- epilogue: x_new = res + br + x[t+d] (x[t+d] from X1s), store fp16
#pragma unroll
  for (int nt=0; nt<2; nt++){
    int t = nt*32 + ln2;
    if (t < ntv){
      size_t xrow = (size_t)b*XSTR + (size_t)(t0+t)*128;
#pragma unroll
      for (int rq=0; rq<4; rq++){
        int c0 = w*32 + rq*8 + 4*h;
        union { ushort4 v; _Float16 hh[4]; } xr;
        xr.v = *(const ushort4*)((const void*)&X1s[(w*4+rq)*520 + t*8 + 4*h]);
        union { _Float16 hh[4]; ushort4 v; } ov;
#pragma unroll
        for (int rr=0; rr<4; rr++)
          ov.hh[rr] = (_Float16)(aC[nt][rq*4+rr] + br_l[c0+rr] + (float)xr.hh[rr]);
        *(ushort4*)((void*)(xout + xrow + c0)) = ov.v;
      }
    }
  }

  // ---- acts -> global B-frag layout indexed by ts
  _Float16* __restrict__ actsB = g_acts + (size_t)l*ALSTR + (size_t)b*ABSTR;
#pragma unroll
  for (int it=0; it<4; it++){
    int t = (tid>>4) + it*16, c16 = tid&15;
    int ts = t0 + t - ss;
    if (t < ntv && ts >= 0 && ts < FOUT_){
      size_t addr = (size_t)(ts>>5)*4096 + (size_t)(c16>>1)*512 + ((c16&1)*32 + (ts&31))*8;
      *(uint4*)((void*)(actsB + addr)) = *(const uint4*)((const void*)&ACs[c16*520 + t*8]);
    }
  }
}

// ---------------- streaming GEMMs: 4-buffer LDS pipeline, 2 blocks/CU ----------------
// MODE 0: skip = Ws[512x2560] @ acts + bssum, relu -> g_skipF (frag)
// MODE 1: h1   = W1[512x512]  @ skipF, relu -> g_h1F (frag)
// MODE 2: out  = W2[256x512]  @ h1F -> fp32 out
// Round-4 pipeline, new XCD-pairing block map (MODE0/1): linear grid, sibling
// m-halves of the same (b,ts) tile at lin and lin+8 -> same lin%8 -> same XCD,
// co-resident and ~8 blocks apart, so the second sibling's B-stream hits the
// XCD-private L2 instead of refetching 148 MB from HBM (round-5 FETCH=2x acts).
//   mhalf = (lin>>3)&1;  pairIdx = (lin>>4)*8 + (lin&7)  (grid padded to 928)
template<int MODE>
__global__ __launch_bounds__(512,4) void gemm_stream(float* __restrict__ outF){
  constexpr int NSTEP = (MODE==0)?160:32;     // k-steps of 16
  constexpr int NSC   = NSTEP/4;              // sub-chunks of 4 ks: 40 or 8
  const _Float16* __restrict__ A    = (MODE==0)?g_WsF:(MODE==1)?g_W1F:g_W2F;
  const _Float16* __restrict__ Bsrc = (MODE==0)?g_acts:(MODE==1)?g_skipF:g_h1F;

  __shared__ __align__(16) _Float16 Bs[4][8192];   // 4 x 16KB

  const int tid = threadIdx.x;
  const int w   = tid >> 6;
  const int lane= tid & 63;
  const int ln2 = lane & 31;
  const int h   = lane >> 5;

  // ---- block mapping (uniform per block; early return before any barrier)
  int lin = blockIdx.x;
  int mhalf, pairIdx;
  if (MODE==2){ mhalf = 0; pairIdx = lin; }
  else {
    mhalf   = (lin>>3)&1;
    pairIdx = ((lin>>4)<<3) | (lin&7);
    if (pairIdx >= 452) return;
  }
  const int b    = pairIdx / 113;
  const int tsb  = pairIdx - b*113;
  const int ts0  = tsb*128;
  const int mtile= mhalf*8 + w;             // this wave's m-tile (32 rows)

  const _Float16* Gq[2];
#pragma unroll
  for (int q=0;q<2;q++){
    int nt = (w*2+q)&3;
    size_t tile = (size_t)tsb*4 + nt;
    Gq[q] = (MODE==0) ? (Bsrc + (size_t)b*ABSTR + tile*4096  + lane*8)
                      : (Bsrc + (size_t)b*SBSTR + tile*16384 + lane*8);
  }

  const _Float16* Aw = A + (size_t)mtile*((size_t)NSTEP*512) + lane*8;

  f32x16 acc[4];
#pragma unroll
  for (int nt=0;nt<4;nt++)
#pragma unroll
    for (int r=0;r<16;r++) acc[nt][r] = 0.f;

  auto STAGE = [&](int buf, int sc){
#pragma unroll
    for (int q=0;q<2;q++){
      int bi   = w*2 + q;
      int kslq = bi>>2;
      const _Float16* g;
      if (MODE==0){
        int ks = sc*4 + kslq;
        g = Gq[q] + (size_t)(ks>>3)*ALSTR + (size_t)(ks&7)*512;
      } else {
        g = Gq[q] + (size_t)(sc*4 + kslq)*512;
      }
      gld_lds16(g, &Bs[buf][(size_t)bi*512]);
    }
  };

  STAGE(0,0);
  STAGE(1,1);
  asm volatile("s_waitcnt vmcnt(2)" ::: "memory");
  __builtin_amdgcn_sched_barrier(0);
  __builtin_amdgcn_s_barrier();

  for (int c=0; c<NSC; ++c){
    const int buf = c & 3;
    f16x8 af[4];
#pragma unroll
    for (int j=0;j<4;j++)
      af[j] = *(const f16x8*)((const void*)(Aw + (size_t)(c*4+j)*512));
    __builtin_amdgcn_sched_barrier(0);
    if (c+2 < NSC) STAGE((c+2)&3, c+2);
    __builtin_amdgcn_sched_barrier(0);
#pragma unroll
    for (int j=0;j<4;j++){
      f16x8 bfr[4];
#pragma unroll
      for (int nt=0;nt<4;nt++)
        bfr[nt] = *(const f16x8*)((const void*)&Bs[buf][(size_t)(j*4+nt)*512 + lane*8]);
#pragma unroll
      for (int nt=0;nt<4;nt++)
        acc[nt] = MFMA32(af[j], bfr[nt], acc[nt]);
    }
    __builtin_amdgcn_sched_barrier(0);
    __builtin_amdgcn_s_barrier();
  }

  if (MODE != 2){
    _Float16* __restrict__ dstb = ((MODE==0)?g_skipF:g_h1F) + (size_t)b*SBSTR;
#pragma unroll
    for (int nt=0; nt<4; nt++){
      int ts = ts0 + nt*32 + ln2;
      if (ts >= FOUT_) continue;
#pragma unroll
      for (int rq=0; rq<4; rq++){
        int m0 = mtile*32 + rq*8 + 4*h;
        union { _Float16 hh[4]; ushort4 v; } pk;
#pragma unroll
        for (int rr=0; rr<4; rr++){
          float vv = acc[nt][rq*4+rr];
          if (MODE==0) vv += g_bssum[m0+rr];
          pk.hh[rr] = (_Float16)fmaxf(vv, 0.f);
        }
        size_t addr = (size_t)(ts>>5)*16384 + (size_t)(mtile*2 + (rq>>1))*512
                    + ((rq&1)*32 + (ts&31))*8 + 4*h;
        *(ushort4*)((void*)(dstb + addr)) = pk.v;
      }
    }
  } else {
#pragma unroll
    for (int nt=0; nt<4; nt++){
      int ts = ts0 + nt*32 + ln2;
      if (ts >= FOUT_) continue;
#pragma unroll
      for (int rq=0; rq<4; rq++){
        int m0 = w*32 + rq*8 + 4*h;
#pragma unroll
        for (int rr=0; rr<4; rr++)
          outF[((size_t)(b*256 + m0 + rr))*FOUT_ + ts] = acc[nt][rq*4+rr];
      }
    }
  }
}

// ---------------- host launch ----------------
extern "C" void kernel_launch(void* const* d_in, const int* in_sizes, int n_in,
                              void* d_out, int out_size, void* d_ws, size_t ws_size,
                              hipStream_t stream) {
  const int*   y     = (const int*)  d_in[0];
  const float* embed = (const float*)d_in[1];
  const float* Wd    = (const float*)d_in[2];
  const float* bd    = (const float*)d_in[3];
  const float* Ws    = (const float*)d_in[4];
  const float* bs    = (const float*)d_in[5];
  const float* Wr    = (const float*)d_in[6];
  const float* br    = (const float*)d_in[7];
  const float* W1    = (const float*)d_in[8];
  const float* W2    = (const float*)d_in[9];
  float* out = (float*)d_out;
  (void)d_ws; (void)ws_size;

  cvt_wd<<<dim3(320), dim3(256), 0, stream>>>(Wd);
  cvt_rm<<<dim3(160), dim3(256), 0, stream>>>(Wr, 0, NL_*128, 128);
  cvt_rm<<<dim3(128), dim3(256), 0, stream>>>(W1, 1, 512, 512);
  cvt_rm<<<dim3( 64), dim3(256), 0, stream>>>(W2, 2, 256, 512);
  cvt_ws<<<dim3(640), dim3(256), 0, stream>>>(Ws);
  bssum_k<<<dim3(1), dim3(512), 0, stream>>>(bs);

  embed_kernel<<<dim3((B_*T_*16)/256), dim3(256), 0, stream>>>(y, embed);

  static const int DIL[NL_] = {1,2,4,8,16,32,64,128,256,512,
                               1,2,4,8,16,32,64,128,256,512};
  int swap = 0;
  int Tin = T_;
  for (int i=0;i<NL_;i++){
    int d = DIL[i];
    int Tout = Tin - d;
    dim3 grid((Tout+63)/64, B_);
    layer16<<<grid, dim3(256), 0, stream>>>(
        swap, i, d, Tout, Tout - FOUT_, bd + (size_t)i*256, br + (size_t)i*128);
    swap ^= 1;
    Tin = Tout;
  }

  // linear grids; MODE0/1 padded to 58*16=928 blocks (pairIdx guard in-kernel)
  gemm_stream<0><<<dim3(928), dim3(512), 0, stream>>>(nullptr);
  gemm_stream<1><<<dim3(928), dim3(512), 0, stream>>>(nullptr);
  gemm_stream<2><<<dim3(452), dim3(512), 0, stream>>>(out);
}